// Round 2
// baseline (1202.547 us; speedup 1.0000x reference)
//
#include <hip/hip_runtime.h>
#include <hip/hip_bf16.h>

#define N_NODES 50000
#define N_EDGES 800000
#define IN_C 128
#define HC 128
#define HEADS 8
#define OUT_C 16
#define NEG_SLOPE 0.2f
#define LN_EPS 1e-5f

typedef __hip_bfloat16 bf16;

__device__ __forceinline__ float b2f(bf16 v) { return __bfloat162float(v); }

// ---------------------------------------------------------------------------
// Stage 1: h = x @ W  (per-node 128x128 GEMV), fused a_src/a_dst head dots.
// One block (128 threads) per node; thread t owns output column t.
// h stored as bf16 (halves gather bytes in stage 3; ~1e-2 abs error, ok).
// ---------------------------------------------------------------------------
__global__ __launch_bounds__(128) void node_phase(
    const float* __restrict__ x, const float* __restrict__ W,
    const float* __restrict__ att_src, const float* __restrict__ att_dst,
    bf16* __restrict__ h_out, float* __restrict__ a_src, float* __restrict__ a_dst)
{
    __shared__ float sx[IN_C];
    const int n = blockIdx.x;
    const int t = threadIdx.x;
    sx[t] = x[(size_t)n * IN_C + t];
    __syncthreads();

    float acc = 0.f;
#pragma unroll 16
    for (int k = 0; k < IN_C; ++k)
        acc += sx[k] * W[k * HC + t];

    h_out[(size_t)n * HC + t] = __float2bfloat16(acc);

    // per-head (groups of 16 contiguous lanes) reduction of h * att
    float vs = acc * att_src[t];
    float vd = acc * att_dst[t];
#pragma unroll
    for (int off = 8; off >= 1; off >>= 1) {
        vs += __shfl_xor(vs, off, 64);
        vd += __shfl_xor(vd, off, 64);
    }
    if ((t & 15) == 0) {
        a_src[n * HEADS + (t >> 4)] = vs;
        a_dst[n * HEADS + (t >> 4)] = vd;
    }
}

// ---------------------------------------------------------------------------
// Stage 2: per-edge logits -> exp -> z[dst,h] accumulation.
// EDGE_DIM == 1 -> a_edge[e,h] = edge_attr[e] * P[h] + Q[h]  (affine)
// Softmax computed without per-segment max shift: logits bounded ~|5|,
// exp stays in fp32 range; softmax is shift-invariant so result matches ref.
// ---------------------------------------------------------------------------
__global__ __launch_bounds__(256) void edge_logits(
    const int* __restrict__ ei, const float* __restrict__ edge_attr,
    const float* __restrict__ att_edge, const float* __restrict__ lin_w,
    const float* __restrict__ lin_b,
    const float* __restrict__ a_src, const float* __restrict__ a_dst,
    float* __restrict__ ex, float* __restrict__ z)
{
    __shared__ float P[HEADS], Q[HEADS];
    const int t = threadIdx.x;
    if (t < 128) {
        float ae = att_edge[t];
        float p = ae * lin_w[t];
        float q = ae * lin_b[t];
#pragma unroll
        for (int off = 8; off >= 1; off >>= 1) {
            p += __shfl_xor(p, off, 64);
            q += __shfl_xor(q, off, 64);
        }
        if ((t & 15) == 0) { P[t >> 4] = p; Q[t >> 4] = q; }
    }
    __syncthreads();

    const int e = blockIdx.x * 256 + t;
    if (e >= N_EDGES) return;
    const int s = ei[e];
    const int d = ei[N_EDGES + e];
    const float ea = edge_attr[e];
    const float* as = a_src + (size_t)s * HEADS;
    const float* ad = a_dst + (size_t)d * HEADS;
#pragma unroll
    for (int hh = 0; hh < HEADS; ++hh) {
        float l = as[hh] + ad[hh] + ea * P[hh] + Q[hh];
        l = l > 0.f ? l : NEG_SLOPE * l;           // leaky_relu
        float ev = __expf(l);
        ex[(size_t)e * HEADS + hh] = ev;
        atomicAdd(&z[(size_t)d * HEADS + hh], ev);
    }
}

// ---------------------------------------------------------------------------
// Stage 3: scatter messages. One wave (64 lanes) per edge; lane covers 2 elems.
// ---------------------------------------------------------------------------
__global__ __launch_bounds__(256) void edge_scatter(
    const int* __restrict__ ei, const bf16* __restrict__ h,
    const float* __restrict__ ex, const float* __restrict__ z,
    float* __restrict__ acc)
{
    const int wave = (blockIdx.x * 256 + threadIdx.x) >> 6;
    const int lane = threadIdx.x & 63;
    if (wave >= N_EDGES) return;
    const int e = wave;
    const int s = ei[e];
    const int d = ei[N_EDGES + e];
    const int head = lane >> 3;                    // elem 2*lane -> head (2*lane)/16
    const float alpha = ex[(size_t)e * HEADS + head] /
                        (z[(size_t)d * HEADS + head] + 1e-16f);

    const __hip_bfloat162* h2 =
        reinterpret_cast<const __hip_bfloat162*>(h + (size_t)s * HC);
    __hip_bfloat162 hv = h2[lane];
    float* dst = acc + (size_t)d * HC + 2 * lane;
    atomicAdd(dst,     alpha * b2f(hv.x));
    atomicAdd(dst + 1, alpha * b2f(hv.y));
}

// ---------------------------------------------------------------------------
// Stage 4: residual + bias + LayerNorm + ELU, fp32 store.
// ---------------------------------------------------------------------------
__global__ __launch_bounds__(128) void finalize(
    const float* __restrict__ acc, const float* __restrict__ x,
    const float* __restrict__ b, const float* __restrict__ gamma,
    const float* __restrict__ beta, float* __restrict__ out)
{
    __shared__ float red[4];
    const int n = blockIdx.x;
    const int t = threadIdx.x;
    const size_t idx = (size_t)n * HC + t;
    float v = acc[idx] + x[idx] + b[t];

    float s = v, ss = v * v;
#pragma unroll
    for (int off = 32; off >= 1; off >>= 1) {
        s  += __shfl_xor(s, off, 64);
        ss += __shfl_xor(ss, off, 64);
    }
    const int w = t >> 6;
    if ((t & 63) == 0) { red[w * 2] = s; red[w * 2 + 1] = ss; }
    __syncthreads();
    s  = red[0] + red[2];
    ss = red[1] + red[3];

    const float mean = s * (1.f / HC);
    const float var  = ss * (1.f / HC) - mean * mean;
    const float inv  = rsqrtf(var + LN_EPS);
    float y = (v - mean) * inv * gamma[t] + beta[t];
    y = y > 0.f ? y : expm1f(y);                   // ELU(alpha=1)
    out[idx] = y;
}

// ---------------------------------------------------------------------------
extern "C" void kernel_launch(void* const* d_in, const int* in_sizes, int n_in,
                              void* d_out, int out_size, void* d_ws, size_t ws_size,
                              hipStream_t stream)
{
    const float* x         = (const float*)d_in[0];
    const int*   ei        = (const int*)d_in[1];
    const float* edge_attr = (const float*)d_in[2];
    const float* W         = (const float*)d_in[3];
    const float* b         = (const float*)d_in[4];
    const float* att_src   = (const float*)d_in[5];
    const float* att_dst   = (const float*)d_in[6];
    const float* att_edge  = (const float*)d_in[7];
    const float* lin_w     = (const float*)d_in[8];
    const float* lin_b     = (const float*)d_in[9];
    const float* gamma     = (const float*)d_in[10];
    const float* beta      = (const float*)d_in[11];

    char* ws = (char*)d_ws;
    bf16*  h     = (bf16*)ws;  ws += (size_t)N_NODES * HC * sizeof(bf16);     // 12.8 MB
    float* a_src = (float*)ws; ws += (size_t)N_NODES * HEADS * sizeof(float); //  1.6 MB
    float* a_dst = (float*)ws; ws += (size_t)N_NODES * HEADS * sizeof(float); //  1.6 MB
    float* ex    = (float*)ws; ws += (size_t)N_EDGES * HEADS * sizeof(float); // 25.6 MB
    float* z     = (float*)ws; ws += (size_t)N_NODES * HEADS * sizeof(float); //  1.6 MB
    float* acc   = (float*)ws; ws += (size_t)N_NODES * HC * sizeof(float);    // 25.6 MB

    hipMemsetAsync(z,   0, (size_t)N_NODES * HEADS * sizeof(float), stream);
    hipMemsetAsync(acc, 0, (size_t)N_NODES * HC * sizeof(float), stream);

    node_phase<<<N_NODES, 128, 0, stream>>>(x, W, att_src, att_dst, h, a_src, a_dst);

    edge_logits<<<(N_EDGES + 255) / 256, 256, 0, stream>>>(
        ei, edge_attr, att_edge, lin_w, lin_b, a_src, a_dst, ex, z);

    // one wave per edge: N_EDGES waves, 4 waves per 256-thread block
    edge_scatter<<<(N_EDGES + 3) / 4, 256, 0, stream>>>(ei, h, ex, z, acc);

    finalize<<<N_NODES, 128, 0, stream>>>(acc, x, b, gamma, beta, (float*)d_out);
}

// Round 3
// 524.316 us; speedup vs baseline: 2.2936x; 2.2936x over previous
//
#include <hip/hip_runtime.h>
#include <hip/hip_bf16.h>

#define N_NODES 50000
#define N_EDGES 800000
#define IN_C 128
#define HC 128
#define HEADS 8
#define OUT_C 16
#define NEG_SLOPE 0.2f
#define LN_EPS 1e-5f

typedef __hip_bfloat16 bf16;

__device__ __forceinline__ float b2f(bf16 v) { return __bfloat162float(v); }

// ---------------------------------------------------------------------------
// Stage 1: h = x @ W  (per-node 128x128 GEMV), fused a_src/a_dst head dots.
// One block (128 threads) per node; thread t owns output column t.
// h stored bf16 (halves gather bytes in the gather kernel; error << threshold).
// ---------------------------------------------------------------------------
__global__ __launch_bounds__(128) void node_phase(
    const float* __restrict__ x, const float* __restrict__ W,
    const float* __restrict__ att_src, const float* __restrict__ att_dst,
    bf16* __restrict__ h_out, float* __restrict__ a_src, float* __restrict__ a_dst)
{
    __shared__ float sx[IN_C];
    const int n = blockIdx.x;
    const int t = threadIdx.x;
    sx[t] = x[(size_t)n * IN_C + t];
    __syncthreads();

    float acc = 0.f;
#pragma unroll 16
    for (int k = 0; k < IN_C; ++k)
        acc += sx[k] * W[k * HC + t];

    h_out[(size_t)n * HC + t] = __float2bfloat16(acc);

    float vs = acc * att_src[t];
    float vd = acc * att_dst[t];
#pragma unroll
    for (int off = 8; off >= 1; off >>= 1) {
        vs += __shfl_xor(vs, off, 64);
        vd += __shfl_xor(vd, off, 64);
    }
    if ((t & 15) == 0) {
        a_src[n * HEADS + (t >> 4)] = vs;
        a_dst[n * HEADS + (t >> 4)] = vd;
    }
}

// ---------------------------------------------------------------------------
// CSR build: count -> scan -> fill.  Int atomics into 0.2 MB (cheap).
// ---------------------------------------------------------------------------
__global__ __launch_bounds__(256) void k_count(
    const int* __restrict__ ei, int* __restrict__ deg)
{
    int e = blockIdx.x * 256 + threadIdx.x;
    if (e < N_EDGES) atomicAdd(&deg[ei[N_EDGES + e]], 1);
}

__global__ __launch_bounds__(1024) void k_scan(
    const int* __restrict__ deg, int* __restrict__ offs)
{
    __shared__ int part[1024];
    const int t = threadIdx.x;
    const int chunk = (N_NODES + 1023) / 1024;   // 49
    const int b0 = t * chunk;
    const int e0 = min(b0 + chunk, N_NODES);
    int sum = 0;
    for (int i = b0; i < e0; ++i) sum += deg[i];
    part[t] = sum;
    __syncthreads();
    for (int off = 1; off < 1024; off <<= 1) {   // inclusive Hillis-Steele
        int v = (t >= off) ? part[t - off] : 0;
        __syncthreads();
        part[t] += v;
        __syncthreads();
    }
    int run = part[t] - sum;                      // exclusive base
    for (int i = b0; i < e0; ++i) { offs[i] = run; run += deg[i]; }
    if (t == 1023) offs[N_NODES] = run;
}

__global__ __launch_bounds__(256) void k_fill(
    const int* __restrict__ ei, const float* __restrict__ edge_attr,
    const int* __restrict__ offs, int* __restrict__ cursor,
    int* __restrict__ csr_src, float* __restrict__ csr_ea)
{
    int e = blockIdx.x * 256 + threadIdx.x;
    if (e >= N_EDGES) return;
    int d = ei[N_EDGES + e];
    int pos = atomicAdd(&cursor[d], 1);
    int slot = offs[d] + pos;
    csr_src[slot] = ei[e];
    csr_ea[slot]  = edge_attr[e];
}

// ---------------------------------------------------------------------------
// Fused per-destination gather: logits+softmax-denom (pass 1), alpha-weighted
// message gather (pass 2), residual+bias+LayerNorm+ELU epilogue. One wave per
// node, lane l owns channels {2l, 2l+1} -> head l>>3. Zero float atomics.
// Segment-softmax without max-shift: logits bounded ~|5|, exp safe in fp32;
// shift-invariance => matches reference (verified: absmax 0.031 in R2).
// ---------------------------------------------------------------------------
__global__ __launch_bounds__(256) void gather_node(
    const int* __restrict__ offs, const int* __restrict__ csr_src,
    const float* __restrict__ csr_ea,
    const float* __restrict__ a_src, const float* __restrict__ a_dst,
    const bf16* __restrict__ h,
    const float* __restrict__ x, const float* __restrict__ bvec,
    const float* __restrict__ gamma, const float* __restrict__ beta,
    const float* __restrict__ att_edge, const float* __restrict__ lin_w,
    const float* __restrict__ lin_b,
    float* __restrict__ out)
{
    const int wave = threadIdx.x >> 6;
    const int l    = threadIdx.x & 63;
    const int n    = blockIdx.x * 4 + wave;       // 50000 % 4 == 0
    const int head = l >> 3;                      // head of channels 2l,2l+1

    // P[head] = sum_c att_edge[h,c]*lin_w[h,c];  Q likewise with lin_b.
    float ae0 = att_edge[2 * l], ae1 = att_edge[2 * l + 1];
    float p = ae0 * lin_w[2 * l] + ae1 * lin_w[2 * l + 1];
    float q = ae0 * lin_b[2 * l] + ae1 * lin_b[2 * l + 1];
#pragma unroll
    for (int off = 1; off <= 4; off <<= 1) {
        p += __shfl_xor(p, off, 64);
        q += __shfl_xor(q, off, 64);
    }

    const float ad  = a_dst[n * HEADS + head];
    const int   beg = offs[n], end = offs[n + 1];

    // Pass 1: softmax denominator z for this lane's head.
    float z = 0.f;
    for (int slot = beg; slot < end; ++slot) {
        int   s  = csr_src[slot];
        float ea = csr_ea[slot];
        float lg = a_src[s * HEADS + head] + ad + ea * p + q;
        lg = lg > 0.f ? lg : NEG_SLOPE * lg;
        z += __expf(lg);
    }
    const float rz = 1.f / (z + 1e-16f);

    // Pass 2: alpha-weighted gather of h[src] (coalesced 256B bf16 rows).
    float acc0 = 0.f, acc1 = 0.f;
    const __hip_bfloat162* h2 = reinterpret_cast<const __hip_bfloat162*>(h);
    for (int slot = beg; slot < end; ++slot) {
        int   s  = csr_src[slot];
        float ea = csr_ea[slot];
        float lg = a_src[s * HEADS + head] + ad + ea * p + q;
        lg = lg > 0.f ? lg : NEG_SLOPE * lg;
        float alpha = __expf(lg) * rz;
        __hip_bfloat162 hv = h2[(size_t)s * 64 + l];
        acc0 += alpha * b2f(hv.x);
        acc1 += alpha * b2f(hv.y);
    }

    // Epilogue: +bias +residual, LayerNorm over 128 channels, ELU, store.
    const size_t idx = (size_t)n * HC + 2 * l;
    float v0 = acc0 + x[idx]     + bvec[2 * l];
    float v1 = acc1 + x[idx + 1] + bvec[2 * l + 1];
    float s1 = v0 + v1, s2 = v0 * v0 + v1 * v1;
#pragma unroll
    for (int off = 32; off >= 1; off >>= 1) {
        s1 += __shfl_xor(s1, off, 64);
        s2 += __shfl_xor(s2, off, 64);
    }
    const float mean = s1 * (1.f / HC);
    const float var  = s2 * (1.f / HC) - mean * mean;
    const float inv  = rsqrtf(var + LN_EPS);
    float y0 = (v0 - mean) * inv * gamma[2 * l]     + beta[2 * l];
    float y1 = (v1 - mean) * inv * gamma[2 * l + 1] + beta[2 * l + 1];
    y0 = y0 > 0.f ? y0 : expm1f(y0);
    y1 = y1 > 0.f ? y1 : expm1f(y1);
    out[idx]     = y0;
    out[idx + 1] = y1;
}

// ---------------------------------------------------------------------------
extern "C" void kernel_launch(void* const* d_in, const int* in_sizes, int n_in,
                              void* d_out, int out_size, void* d_ws, size_t ws_size,
                              hipStream_t stream)
{
    const float* x         = (const float*)d_in[0];
    const int*   ei        = (const int*)d_in[1];
    const float* edge_attr = (const float*)d_in[2];
    const float* W         = (const float*)d_in[3];
    const float* b         = (const float*)d_in[4];
    const float* att_src   = (const float*)d_in[5];
    const float* att_dst   = (const float*)d_in[6];
    const float* att_edge  = (const float*)d_in[7];
    const float* lin_w     = (const float*)d_in[8];
    const float* lin_b     = (const float*)d_in[9];
    const float* gamma     = (const float*)d_in[10];
    const float* beta      = (const float*)d_in[11];

    char* ws = (char*)d_ws;
    bf16*  h       = (bf16*)ws;  ws += (size_t)N_NODES * HC * sizeof(bf16);     // 12.8 MB
    float* a_src   = (float*)ws; ws += (size_t)N_NODES * HEADS * sizeof(float); //  1.6 MB
    float* a_dst   = (float*)ws; ws += (size_t)N_NODES * HEADS * sizeof(float); //  1.6 MB
    int*   deg     = (int*)ws;   ws += (size_t)N_NODES * sizeof(int);           //  0.2 MB
    int*   cursor  = (int*)ws;   ws += (size_t)N_NODES * sizeof(int);           //  0.2 MB
    int*   offs    = (int*)ws;   ws += (size_t)(N_NODES + 1) * sizeof(int);     //  0.2 MB
    int*   csr_src = (int*)ws;   ws += (size_t)N_EDGES * sizeof(int);           //  3.2 MB
    float* csr_ea  = (float*)ws; ws += (size_t)N_EDGES * sizeof(float);         //  3.2 MB

    hipMemsetAsync(deg,    0, (size_t)N_NODES * sizeof(int), stream);
    hipMemsetAsync(cursor, 0, (size_t)N_NODES * sizeof(int), stream);

    k_count<<<(N_EDGES + 255) / 256, 256, 0, stream>>>(ei, deg);
    k_scan<<<1, 1024, 0, stream>>>(deg, offs);
    k_fill<<<(N_EDGES + 255) / 256, 256, 0, stream>>>(ei, edge_attr, offs, cursor,
                                                      csr_src, csr_ea);

    node_phase<<<N_NODES, 128, 0, stream>>>(x, W, att_src, att_dst, h, a_src, a_dst);

    gather_node<<<N_NODES / 4, 256, 0, stream>>>(
        offs, csr_src, csr_ea, a_src, a_dst, h, x, b, gamma, beta,
        att_edge, lin_w, lin_b, (float*)d_out);
}

// Round 4
// 331.050 us; speedup vs baseline: 3.6325x; 1.5838x over previous
//
#include <hip/hip_runtime.h>
#include <hip/hip_bf16.h>

#define N_NODES 50000
#define N_EDGES 800000
#define IN_C 128
#define HC 128
#define HEADS 8
#define OUT_C 16
#define NEG_SLOPE 0.2f
#define LN_EPS 1e-5f
#define NB 8            // nodes per node_phase block

typedef __hip_bfloat16 bf16;

__device__ __forceinline__ float b2f(bf16 v) { return __bfloat162float(v); }

// ---------------------------------------------------------------------------
// Stage 1: h = x @ W, register-tiled: 8 nodes/block, thread t owns column t
// with 8 accumulators -> each W element loaded once serves 8 FMAs.
// Fused: per-dst degree count (grid*128 == N_EDGES exactly).
// ---------------------------------------------------------------------------
__global__ __launch_bounds__(128) void node_phase(
    const float* __restrict__ x, const float* __restrict__ W,
    const float* __restrict__ att_src, const float* __restrict__ att_dst,
    const int* __restrict__ ei, int* __restrict__ deg,
    bf16* __restrict__ h_out, float* __restrict__ a_src, float* __restrict__ a_dst)
{
    __shared__ __align__(16) float sx[NB][IN_C];
    const int t  = threadIdx.x;
    const int n0 = blockIdx.x * NB;

    // fused CSR degree count: one edge per thread, hidden under GEMV compute
    {
        int e = blockIdx.x * 128 + t;
        atomicAdd(&deg[ei[N_EDGES + e]], 1);
    }

#pragma unroll
    for (int j = 0; j < NB; ++j)
        sx[j][t] = x[(size_t)(n0 + j) * IN_C + t];
    __syncthreads();

    float acc[NB];
#pragma unroll
    for (int j = 0; j < NB; ++j) acc[j] = 0.f;

#pragma unroll 2
    for (int k = 0; k < IN_C; k += 4) {
        float w0 = W[(k + 0) * HC + t];
        float w1 = W[(k + 1) * HC + t];
        float w2 = W[(k + 2) * HC + t];
        float w3 = W[(k + 3) * HC + t];
#pragma unroll
        for (int j = 0; j < NB; ++j) {
            float4 s4 = *reinterpret_cast<const float4*>(&sx[j][k]);
            acc[j] = fmaf(s4.x, w0, acc[j]);
            acc[j] = fmaf(s4.y, w1, acc[j]);
            acc[j] = fmaf(s4.z, w2, acc[j]);
            acc[j] = fmaf(s4.w, w3, acc[j]);
        }
    }

    const float as_t = att_src[t], ad_t = att_dst[t];
#pragma unroll
    for (int j = 0; j < NB; ++j) {
        float a = acc[j];
        h_out[(size_t)(n0 + j) * HC + t] = __float2bfloat16(a);
        float vs = a * as_t, vd = a * ad_t;
#pragma unroll
        for (int off = 8; off >= 1; off >>= 1) {
            vs += __shfl_xor(vs, off, 64);
            vd += __shfl_xor(vd, off, 64);
        }
        if ((t & 15) == 0) {
            a_src[(n0 + j) * HEADS + (t >> 4)] = vs;
            a_dst[(n0 + j) * HEADS + (t >> 4)] = vd;
        }
    }
}

// ---------------------------------------------------------------------------
// CSR scan + fill (count fused into node_phase). csr packs {src, edge_attr}.
// ---------------------------------------------------------------------------
__global__ __launch_bounds__(1024) void k_scan(
    const int* __restrict__ deg, int* __restrict__ offs)
{
    __shared__ int part[1024];
    const int t = threadIdx.x;
    const int chunk = (N_NODES + 1023) / 1024;   // 49
    const int b0 = t * chunk;
    const int e0 = min(b0 + chunk, N_NODES);
    int sum = 0;
    for (int i = b0; i < e0; ++i) sum += deg[i];
    part[t] = sum;
    __syncthreads();
    for (int off = 1; off < 1024; off <<= 1) {   // inclusive Hillis-Steele
        int v = (t >= off) ? part[t - off] : 0;
        __syncthreads();
        part[t] += v;
        __syncthreads();
    }
    int run = part[t] - sum;                      // exclusive base
    for (int i = b0; i < e0; ++i) { offs[i] = run; run += deg[i]; }
    if (t == 1023) offs[N_NODES] = run;
}

__global__ __launch_bounds__(256) void k_fill(
    const int* __restrict__ ei, const float* __restrict__ edge_attr,
    const int* __restrict__ offs, int* __restrict__ cursor,
    int2* __restrict__ csr)
{
    int e = blockIdx.x * 256 + threadIdx.x;
    if (e >= N_EDGES) return;
    int d = ei[N_EDGES + e];
    int pos = atomicAdd(&cursor[d], 1);
    csr[offs[d] + pos] = make_int2(ei[e], __float_as_int(edge_attr[e]));
}

// ---------------------------------------------------------------------------
// Fused gather: single-pass online softmax (normalize at end — linearity),
// wave-parallel logits: chunk of 8 edges; lane l computes exp for
// (edge l&7, head l>>3) = 64 (edge,head) pairs at once; h-row FMAs are 8
// independent coalesced 256B loads per chunk. Epilogue: residual+LN+ELU.
// ---------------------------------------------------------------------------
__global__ __launch_bounds__(256) void gather_node(
    const int* __restrict__ offs, const int2* __restrict__ csr,
    const float* __restrict__ a_src, const float* __restrict__ a_dst,
    const bf16* __restrict__ h,
    const float* __restrict__ x, const float* __restrict__ bvec,
    const float* __restrict__ gamma, const float* __restrict__ beta,
    const float* __restrict__ att_edge, const float* __restrict__ lin_w,
    const float* __restrict__ lin_b,
    float* __restrict__ out)
{
    const int wave = threadIdx.x >> 6;
    const int l    = threadIdx.x & 63;
    const int n    = blockIdx.x * 4 + wave;       // 50000 % 4 == 0
    const int hh   = l >> 3;                      // head (logits AND channels)
    const int jj   = l & 7;                       // edge-in-chunk for logits

    // P[h] = <att_edge[h,:], lin_w[h,:]>, Q[h] likewise with lin_b.
    float ae0 = att_edge[2 * l], ae1 = att_edge[2 * l + 1];
    float p = ae0 * lin_w[2 * l] + ae1 * lin_w[2 * l + 1];
    float q = ae0 * lin_b[2 * l] + ae1 * lin_b[2 * l + 1];
#pragma unroll
    for (int off = 1; off <= 4; off <<= 1) {
        p += __shfl_xor(p, off, 64);
        q += __shfl_xor(q, off, 64);
    }

    const float ad  = a_dst[n * HEADS + hh];
    const int   beg = offs[n], end = offs[n + 1];

    float z = 0.f, acc0 = 0.f, acc1 = 0.f;
    const __hip_bfloat162* h2 = reinterpret_cast<const __hip_bfloat162*>(h);

    for (int base = beg; base < end; base += 8) {
        const int  slot = base + jj;
        const bool v    = slot < end;
        int  sl = 0; float ea = 0.f, ev = 0.f;
        if (v) {
            int2 ce = csr[slot];
            sl = ce.x;
            ea = __int_as_float(ce.y);
            float lg = a_src[sl * HEADS + hh] + ad + ea * p + q;
            lg = lg > 0.f ? lg : NEG_SLOPE * lg;
            ev = __expf(lg);
        }
        // softmax denom: sum ev over the 8 lanes of this head group
        float zs = ev;
        zs += __shfl_xor(zs, 1, 64);
        zs += __shfl_xor(zs, 2, 64);
        zs += __shfl_xor(zs, 4, 64);
        z += zs;

        const int cnt = min(8, end - base);       // wave-uniform
        const int gbase = l & 56;                 // my head group's lane base
        if (cnt == 8) {
#pragma unroll
            for (int j = 0; j < 8; ++j) {
                float evj = __shfl(ev, gbase | j, 64);
                int   sj  = __shfl(sl, gbase | j, 64);
                __hip_bfloat162 hv = h2[(size_t)sj * 64 + l];
                acc0 += evj * b2f(hv.x);
                acc1 += evj * b2f(hv.y);
            }
        } else {
            for (int j = 0; j < cnt; ++j) {
                float evj = __shfl(ev, gbase | j, 64);
                int   sj  = __shfl(sl, gbase | j, 64);
                __hip_bfloat162 hv = h2[(size_t)sj * 64 + l];
                acc0 += evj * b2f(hv.x);
                acc1 += evj * b2f(hv.y);
            }
        }
    }
    const float rz = 1.f / (z + 1e-16f);
    acc0 *= rz;
    acc1 *= rz;

    // Epilogue: +bias +residual, LayerNorm over 128 channels, ELU, store.
    const size_t idx = (size_t)n * HC + 2 * l;
    const float2 xv = *reinterpret_cast<const float2*>(x + idx);
    const float2 bv = *reinterpret_cast<const float2*>(bvec + 2 * l);
    float v0 = acc0 + xv.x + bv.x;
    float v1 = acc1 + xv.y + bv.y;
    float s1 = v0 + v1, s2 = v0 * v0 + v1 * v1;
#pragma unroll
    for (int off = 32; off >= 1; off >>= 1) {
        s1 += __shfl_xor(s1, off, 64);
        s2 += __shfl_xor(s2, off, 64);
    }
    const float mean = s1 * (1.f / HC);
    const float var  = s2 * (1.f / HC) - mean * mean;
    const float inv  = rsqrtf(var + LN_EPS);
    const float2 gv = *reinterpret_cast<const float2*>(gamma + 2 * l);
    const float2 be = *reinterpret_cast<const float2*>(beta + 2 * l);
    float y0 = (v0 - mean) * inv * gv.x + be.x;
    float y1 = (v1 - mean) * inv * gv.y + be.y;
    y0 = y0 > 0.f ? y0 : expm1f(y0);
    y1 = y1 > 0.f ? y1 : expm1f(y1);
    *reinterpret_cast<float2*>(out + idx) = make_float2(y0, y1);
}

// ---------------------------------------------------------------------------
extern "C" void kernel_launch(void* const* d_in, const int* in_sizes, int n_in,
                              void* d_out, int out_size, void* d_ws, size_t ws_size,
                              hipStream_t stream)
{
    const float* x         = (const float*)d_in[0];
    const int*   ei        = (const int*)d_in[1];
    const float* edge_attr = (const float*)d_in[2];
    const float* W         = (const float*)d_in[3];
    const float* b         = (const float*)d_in[4];
    const float* att_src   = (const float*)d_in[5];
    const float* att_dst   = (const float*)d_in[6];
    const float* att_edge  = (const float*)d_in[7];
    const float* lin_w     = (const float*)d_in[8];
    const float* lin_b     = (const float*)d_in[9];
    const float* gamma     = (const float*)d_in[10];
    const float* beta      = (const float*)d_in[11];

    char* ws = (char*)d_ws;
    bf16*  h       = (bf16*)ws;  ws += (size_t)N_NODES * HC * sizeof(bf16);     // 12.8 MB
    float* a_src   = (float*)ws; ws += (size_t)N_NODES * HEADS * sizeof(float); //  1.6 MB
    float* a_dst   = (float*)ws; ws += (size_t)N_NODES * HEADS * sizeof(float); //  1.6 MB
    int*   deg     = (int*)ws;   ws += (size_t)N_NODES * sizeof(int);           //  0.2 MB
    int*   cursor  = (int*)ws;   ws += (size_t)N_NODES * sizeof(int);           //  0.2 MB
    int*   offs    = (int*)ws;   ws += (size_t)(N_NODES + 1) * sizeof(int);     //  0.2 MB
    int2*  csr     = (int2*)ws;  ws += (size_t)N_EDGES * sizeof(int2);          //  6.4 MB

    hipMemsetAsync(deg,    0, (size_t)N_NODES * sizeof(int), stream);
    hipMemsetAsync(cursor, 0, (size_t)N_NODES * sizeof(int), stream);

    node_phase<<<N_NODES / NB, 128, 0, stream>>>(
        x, W, att_src, att_dst, ei, deg, h, a_src, a_dst);

    k_scan<<<1, 1024, 0, stream>>>(deg, offs);
    k_fill<<<(N_EDGES + 255) / 256, 256, 0, stream>>>(ei, edge_attr, offs, cursor, csr);

    gather_node<<<N_NODES / 4, 256, 0, stream>>>(
        offs, csr, a_src, a_dst, h, x, b, gamma, beta,
        att_edge, lin_w, lin_b, (float*)d_out);
}

// Round 5
// 247.049 us; speedup vs baseline: 4.8677x; 1.3400x over previous
//
#include <hip/hip_runtime.h>
#include <hip/hip_bf16.h>

#define N_NODES 50000
#define N_EDGES 800000
#define IN_C 128
#define HC 128
#define HEADS 8
#define OUT_C 16
#define NEG_SLOPE 0.2f
#define LN_EPS 1e-5f
#define NB 8                    // nodes per node_phase block
#define SCAN_BLOCKS 196         // ceil(50176/256); covers padded range

typedef __hip_bfloat16 bf16;

__device__ __forceinline__ float b2f(bf16 v) { return __bfloat162float(v); }

// ---------------------------------------------------------------------------
// Stage 1: h = x @ W, register-tiled: 8 nodes/block, thread t owns column t
// with 8 accumulators. Fused: per-dst degree count (grid*128 == N_EDGES).
// ---------------------------------------------------------------------------
__global__ __launch_bounds__(128) void node_phase(
    const float* __restrict__ x, const float* __restrict__ W,
    const float* __restrict__ att_src, const float* __restrict__ att_dst,
    const int* __restrict__ ei, int* __restrict__ deg,
    bf16* __restrict__ h_out, float* __restrict__ a_src, float* __restrict__ a_dst)
{
    __shared__ __align__(16) float sx[NB][IN_C];
    const int t  = threadIdx.x;
    const int n0 = blockIdx.x * NB;

    {   // fused CSR degree count, hidden under GEMV compute
        int e = blockIdx.x * 128 + t;
        atomicAdd(&deg[ei[N_EDGES + e]], 1);
    }

#pragma unroll
    for (int j = 0; j < NB; ++j)
        sx[j][t] = x[(size_t)(n0 + j) * IN_C + t];
    __syncthreads();

    float acc[NB];
#pragma unroll
    for (int j = 0; j < NB; ++j) acc[j] = 0.f;

#pragma unroll 2
    for (int k = 0; k < IN_C; k += 4) {
        float w0 = W[(k + 0) * HC + t];
        float w1 = W[(k + 1) * HC + t];
        float w2 = W[(k + 2) * HC + t];
        float w3 = W[(k + 3) * HC + t];
#pragma unroll
        for (int j = 0; j < NB; ++j) {
            float4 s4 = *reinterpret_cast<const float4*>(&sx[j][k]);
            acc[j] = fmaf(s4.x, w0, acc[j]);
            acc[j] = fmaf(s4.y, w1, acc[j]);
            acc[j] = fmaf(s4.z, w2, acc[j]);
            acc[j] = fmaf(s4.w, w3, acc[j]);
        }
    }

    const float as_t = att_src[t], ad_t = att_dst[t];
#pragma unroll
    for (int j = 0; j < NB; ++j) {
        float a = acc[j];
        h_out[(size_t)(n0 + j) * HC + t] = __float2bfloat16(a);
        float vs = a * as_t, vd = a * ad_t;
#pragma unroll
        for (int off = 8; off >= 1; off >>= 1) {
            vs += __shfl_xor(vs, off, 64);
            vd += __shfl_xor(vd, off, 64);
        }
        if ((t & 15) == 0) {
            a_src[(n0 + j) * HEADS + (t >> 4)] = vs;
            a_dst[(n0 + j) * HEADS + (t >> 4)] = vd;
        }
    }
}

// ---------------------------------------------------------------------------
// Hierarchical scan, stage 1: per-block (256-elem) exclusive scan.
// Writes local[], blocksum[], and RE-ZEROES deg so k_fill reuses it as cursor.
// ---------------------------------------------------------------------------
__global__ __launch_bounds__(256) void scan_local(
    int* __restrict__ deg, int* __restrict__ local, int* __restrict__ blocksum)
{
    __shared__ int wtot[4], wbase[4];
    const int t    = threadIdx.x;
    const int lane = t & 63;
    const int i    = blockIdx.x * 256 + t;
    const int d    = (i < N_NODES) ? deg[i] : 0;

    int inc = d;                              // wave-inclusive scan
#pragma unroll
    for (int off = 1; off < 64; off <<= 1) {
        int v = __shfl_up(inc, off, 64);
        if (lane >= off) inc += v;
    }
    if (lane == 63) wtot[t >> 6] = inc;
    __syncthreads();
    if (t == 0) {
        int r = 0;
#pragma unroll
        for (int w = 0; w < 4; ++w) { wbase[w] = r; r += wtot[w]; }
    }
    __syncthreads();

    local[i] = inc - d + wbase[t >> 6];       // exclusive within block
    if (t == 255) blocksum[blockIdx.x] = wbase[3] + wtot[3];
    if (i < N_NODES) deg[i] = 0;              // becomes k_fill's cursor
}

// Stage 2: exclusive scan of the 196 block sums (single block).
__global__ __launch_bounds__(256) void scan_base(
    const int* __restrict__ blocksum, int* __restrict__ base)
{
    __shared__ int wtot[4], wbase[4];
    const int t    = threadIdx.x;
    const int lane = t & 63;
    const int d    = (t < SCAN_BLOCKS) ? blocksum[t] : 0;

    int inc = d;
#pragma unroll
    for (int off = 1; off < 64; off <<= 1) {
        int v = __shfl_up(inc, off, 64);
        if (lane >= off) inc += v;
    }
    if (lane == 63) wtot[t >> 6] = inc;
    __syncthreads();
    if (t == 0) {
        int r = 0;
#pragma unroll
        for (int w = 0; w < 4; ++w) { wbase[w] = r; r += wtot[w]; }
    }
    __syncthreads();
    if (t < SCAN_BLOCKS) base[t] = inc - d + wbase[t >> 6];
}

// ---------------------------------------------------------------------------
// CSR fill. offs(i) = local[i] + base[i>>8]; deg (re-zeroed) is the cursor.
// ---------------------------------------------------------------------------
__global__ __launch_bounds__(256) void k_fill(
    const int* __restrict__ ei, const float* __restrict__ edge_attr,
    const int* __restrict__ local, const int* __restrict__ base,
    int* __restrict__ deg, int2* __restrict__ csr)
{
    int e = blockIdx.x * 256 + threadIdx.x;
    if (e >= N_EDGES) return;
    int d = ei[N_EDGES + e];
    int pos = atomicAdd(&deg[d], 1);
    int slot = local[d] + base[d >> 8] + pos;
    csr[slot] = make_int2(ei[e], __float_as_int(edge_attr[e]));
}

// ---------------------------------------------------------------------------
// Fused gather: single-pass softmax (normalize at end), wave-parallel logits
// (8 edges x 8 heads per chunk), coalesced 256B h-row FMAs, fused epilogue.
// ---------------------------------------------------------------------------
__global__ __launch_bounds__(256) void gather_node(
    const int* __restrict__ local, const int* __restrict__ base,
    const int2* __restrict__ csr,
    const float* __restrict__ a_src, const float* __restrict__ a_dst,
    const bf16* __restrict__ h,
    const float* __restrict__ x, const float* __restrict__ bvec,
    const float* __restrict__ gamma, const float* __restrict__ beta,
    const float* __restrict__ att_edge, const float* __restrict__ lin_w,
    const float* __restrict__ lin_b,
    float* __restrict__ out)
{
    const int wave = threadIdx.x >> 6;
    const int l    = threadIdx.x & 63;
    const int n    = blockIdx.x * 4 + wave;       // 50000 % 4 == 0
    const int hh   = l >> 3;                      // head (logits AND channels)
    const int jj   = l & 7;                       // edge-in-chunk for logits

    // P[h] = <att_edge[h,:], lin_w[h,:]>, Q[h] likewise with lin_b.
    float ae0 = att_edge[2 * l], ae1 = att_edge[2 * l + 1];
    float p = ae0 * lin_w[2 * l] + ae1 * lin_w[2 * l + 1];
    float q = ae0 * lin_b[2 * l] + ae1 * lin_b[2 * l + 1];
#pragma unroll
    for (int off = 1; off <= 4; off <<= 1) {
        p += __shfl_xor(p, off, 64);
        q += __shfl_xor(q, off, 64);
    }

    const float ad  = a_dst[n * HEADS + hh];
    const int   beg = local[n]     + base[n >> 8];
    const int   end = local[n + 1] + base[(n + 1) >> 8];

    float z = 0.f, acc0 = 0.f, acc1 = 0.f;
    const __hip_bfloat162* h2 = reinterpret_cast<const __hip_bfloat162*>(h);

    for (int bs = beg; bs < end; bs += 8) {
        const int  slot = bs + jj;
        const bool v    = slot < end;
        int  sl = 0; float ev = 0.f;
        if (v) {
            int2 ce = csr[slot];
            sl = ce.x;
            float ea = __int_as_float(ce.y);
            float lg = a_src[sl * HEADS + hh] + ad + ea * p + q;
            lg = lg > 0.f ? lg : NEG_SLOPE * lg;
            ev = __expf(lg);
        }
        float zs = ev;                            // denom over 8 head-lanes
        zs += __shfl_xor(zs, 1, 64);
        zs += __shfl_xor(zs, 2, 64);
        zs += __shfl_xor(zs, 4, 64);
        z += zs;

        const int cnt = min(8, end - bs);         // wave-uniform
        const int gbase = l & 56;                 // my head group's lane base
        if (cnt == 8) {
#pragma unroll
            for (int j = 0; j < 8; ++j) {
                float evj = __shfl(ev, gbase | j, 64);
                int   sj  = __shfl(sl, gbase | j, 64);
                __hip_bfloat162 hv = h2[(size_t)sj * 64 + l];
                acc0 += evj * b2f(hv.x);
                acc1 += evj * b2f(hv.y);
            }
        } else {
            for (int j = 0; j < cnt; ++j) {
                float evj = __shfl(ev, gbase | j, 64);
                int   sj  = __shfl(sl, gbase | j, 64);
                __hip_bfloat162 hv = h2[(size_t)sj * 64 + l];
                acc0 += evj * b2f(hv.x);
                acc1 += evj * b2f(hv.y);
            }
        }
    }
    const float rz = 1.f / (z + 1e-16f);
    acc0 *= rz;
    acc1 *= rz;

    // Epilogue: +bias +residual, LayerNorm over 128 channels, ELU, store.
    const size_t idx = (size_t)n * HC + 2 * l;
    const float2 xv = *reinterpret_cast<const float2*>(x + idx);
    const float2 bv = *reinterpret_cast<const float2*>(bvec + 2 * l);
    float v0 = acc0 + xv.x + bv.x;
    float v1 = acc1 + xv.y + bv.y;
    float s1 = v0 + v1, s2 = v0 * v0 + v1 * v1;
#pragma unroll
    for (int off = 32; off >= 1; off >>= 1) {
        s1 += __shfl_xor(s1, off, 64);
        s2 += __shfl_xor(s2, off, 64);
    }
    const float mean = s1 * (1.f / HC);
    const float var  = s2 * (1.f / HC) - mean * mean;
    const float inv  = rsqrtf(var + LN_EPS);
    const float2 gv = *reinterpret_cast<const float2*>(gamma + 2 * l);
    const float2 be = *reinterpret_cast<const float2*>(beta + 2 * l);
    float y0 = (v0 - mean) * inv * gv.x + be.x;
    float y1 = (v1 - mean) * inv * gv.y + be.y;
    y0 = y0 > 0.f ? y0 : expm1f(y0);
    y1 = y1 > 0.f ? y1 : expm1f(y1);
    *reinterpret_cast<float2*>(out + idx) = make_float2(y0, y1);
}

// ---------------------------------------------------------------------------
extern "C" void kernel_launch(void* const* d_in, const int* in_sizes, int n_in,
                              void* d_out, int out_size, void* d_ws, size_t ws_size,
                              hipStream_t stream)
{
    const float* x         = (const float*)d_in[0];
    const int*   ei        = (const int*)d_in[1];
    const float* edge_attr = (const float*)d_in[2];
    const float* W         = (const float*)d_in[3];
    const float* b         = (const float*)d_in[4];
    const float* att_src   = (const float*)d_in[5];
    const float* att_dst   = (const float*)d_in[6];
    const float* att_edge  = (const float*)d_in[7];
    const float* lin_w     = (const float*)d_in[8];
    const float* lin_b     = (const float*)d_in[9];
    const float* gamma     = (const float*)d_in[10];
    const float* beta      = (const float*)d_in[11];

    char* ws = (char*)d_ws;
    bf16*  h        = (bf16*)ws; ws += (size_t)N_NODES * HC * sizeof(bf16);     // 12.8 MB
    float* a_src    = (float*)ws; ws += (size_t)N_NODES * HEADS * sizeof(float); // 1.6 MB
    float* a_dst    = (float*)ws; ws += (size_t)N_NODES * HEADS * sizeof(float); // 1.6 MB
    int*   deg      = (int*)ws;   ws += (size_t)N_NODES * sizeof(int);           // 0.2 MB
    int*   local    = (int*)ws;   ws += (size_t)(SCAN_BLOCKS * 256) * sizeof(int);
    int*   blocksum = (int*)ws;   ws += (size_t)SCAN_BLOCKS * sizeof(int);
    int*   base     = (int*)ws;   ws += (size_t)((SCAN_BLOCKS + 63) & ~63) * sizeof(int);
    int2*  csr      = (int2*)ws;  ws += (size_t)N_EDGES * sizeof(int2);          // 6.4 MB

    hipMemsetAsync(deg, 0, (size_t)N_NODES * sizeof(int), stream);

    node_phase<<<N_NODES / NB, 128, 0, stream>>>(
        x, W, att_src, att_dst, ei, deg, h, a_src, a_dst);

    scan_local<<<SCAN_BLOCKS, 256, 0, stream>>>(deg, local, blocksum);
    scan_base<<<1, 256, 0, stream>>>(blocksum, base);
    k_fill<<<(N_EDGES + 255) / 256, 256, 0, stream>>>(ei, edge_attr, local, base,
                                                      deg, csr);

    gather_node<<<N_NODES / 4, 256, 0, stream>>>(
        local, base, csr, a_src, a_dst, h, x, b, gamma, beta,
        att_edge, lin_w, lin_b, (float*)d_out);
}